// Round 9
// baseline (327.014 us; speedup 1.0000x reference)
//
#include <hip/hip_runtime.h>

// B=2 S=8192 E=1024 H=16 D=64 CHUNK=128 NC=64

using h16   = _Float16;
using h16x8 = __attribute__((ext_vector_type(8))) _Float16;
using h16x4 = __attribute__((ext_vector_type(4))) _Float16;
using f32x4 = __attribute__((ext_vector_type(4))) float;

#define MFMA16(a,b,c) __builtin_amdgcn_mfma_f32_16x16x32_f16(a,b,c,0,0,0)

#define GLOAD16(gp, lp) __builtin_amdgcn_global_load_lds( \
    (const __attribute__((address_space(1))) void*)(gp),  \
    (__attribute__((address_space(3))) void*)(lp), 16, 0, 0)

// RoPE on 8 contiguous dims starting at even d0: fp = fc + s*64 + d0.
__device__ __forceinline__ h16x8 rope8(h16x8 v, const float* __restrict__ fp) {
  float4 f0 = *(const float4*)fp;
  float4 f1 = *(const float4*)(fp + 4);
  h16x8 o; float x0, x1;
  x0=(float)v[0]; x1=(float)v[1]; o[0]=(h16)(x0*f0.x - x1*f0.y); o[1]=(h16)(x1*f0.x + x0*f0.y);
  x0=(float)v[2]; x1=(float)v[3]; o[2]=(h16)(x0*f0.z - x1*f0.w); o[3]=(h16)(x1*f0.z + x0*f0.w);
  x0=(float)v[4]; x1=(float)v[5]; o[4]=(h16)(x0*f1.x - x1*f1.y); o[5]=(h16)(x1*f1.x + x0*f1.y);
  x0=(float)v[6]; x1=(float)v[7]; o[6]=(h16)(x0*f1.z - x1*f1.w); o[7]=(h16)(x1*f1.z + x0*f1.w);
  return o;
}

// ---------------- fp32 -> fp16 convert (8 elems/thread) ----------------
__global__ __launch_bounds__(256) void k_cvt(const float* __restrict__ s,
                                             h16* __restrict__ d, int n) {
  int i = (blockIdx.x * 256 + threadIdx.x) * 8;
  if (i >= n) return;
  float4 a = *(const float4*)(s + i);
  float4 b = *(const float4*)(s + i + 4);
  h16x8 o;
  o[0]=(h16)a.x; o[1]=(h16)a.y; o[2]=(h16)a.z; o[3]=(h16)a.w;
  o[4]=(h16)b.x; o[5]=(h16)b.y; o[6]=(h16)b.z; o[7]=(h16)b.w;
  *(h16x8*)(d + i) = o;
}

// ===== 256x256 GEMM mainloop v3: BK=32, 4-deep ring, phase-split =====
// 8 waves (2M x 4N), per-wave out 128x64. LDS 128 KiB = 4 bufs x 32 KB
// (A 16 KB + B 16 KB per buf). Tile layout: r4-proven packed rows —
// logical [256 rows][4 slots of 8 h16], phys granule (p=R>>1,
// q=((R&1)*4+s)^(p&7)) at byte p*128+q*16 (measured 0 conflicts).
// Per K-tile t: {8 ds_read | stage A(t+2) | lgkm(0) | 16 MFMA}
//              {4 ds_read | stage B(t+2) | lgkm(0) | 16 MFMA}
//              vmcnt(4) ; s_barrier          (ONE barrier per K-tile)
// 4-deep ring => staging t+2 never collides with tile-t reads.
__device__ __forceinline__ void gemm256_loop(
    const h16* __restrict__ At, const h16* __restrict__ Bt,
    char* smem, int w, int l, f32x4 (&acc)[8][4])
{
  const int tid = w*64 + l;
  const int wr = w >> 2, wc = w & 3;

  // staging granule maps: instr c covers granules G = c*512 + tid
  size_t gof[2];
  #pragma unroll
  for (int c = 0; c < 2; c++) {
    int G = c*512 + tid;
    int pp = G >> 3;
    int idx = (G & 7) ^ (pp & 7);
    gof[c] = (size_t)(2*pp + (idx >> 2))*1024 + (idx & 3)*8;
  }

  // fragment read offsets (per-lane constants)
  const int q16 = ((((l & 1) << 2) | (l >> 4)) ^ ((l >> 1) & 7)) * 16;
  const int abyte = wr*8192 + ((l >> 1) & 7)*128 + q16;          // + mf*1024
  const int bbyte = 16384 + wc*4096 + ((l >> 1) & 7)*128 + q16;  // + nf*1024

  auto stageA = [&](int kt) {
    char* buf = smem + (kt & 3)*32768;
    #pragma unroll
    for (int c = 0; c < 2; c++)
      GLOAD16(At + gof[c] + kt*32, buf + c*8192 + w*1024);
  };
  auto stageB = [&](int kt) {
    char* buf = smem + (kt & 3)*32768;
    #pragma unroll
    for (int c = 0; c < 2; c++)
      GLOAD16(Bt + gof[c] + kt*32, buf + 16384 + c*8192 + w*1024);
  };

  stageA(0); stageB(0); stageA(1); stageB(1);
  asm volatile("s_waitcnt vmcnt(4)" ::: "memory");   // tile0 landed
  __builtin_amdgcn_sched_barrier(0);
  __builtin_amdgcn_s_barrier();

  for (int t = 0; t < 32; ++t) {
    const char* buf = smem + (t & 3)*32768;
    h16x8 af[8], bf[4];
    // ---- phase A ----
    #pragma unroll
    for (int mf = 0; mf < 4; mf++) af[mf] = *(const h16x8*)(buf + abyte + mf*1024);
    #pragma unroll
    for (int nf = 0; nf < 4; nf++) bf[nf] = *(const h16x8*)(buf + bbyte + nf*1024);
    if (t < 30) stageA(t + 2);
    asm volatile("s_waitcnt lgkmcnt(0)" ::: "memory");
    __builtin_amdgcn_sched_barrier(0);
    __builtin_amdgcn_s_setprio(1);
    #pragma unroll
    for (int mf = 0; mf < 4; mf++)
      #pragma unroll
      for (int nf = 0; nf < 4; nf++)
        acc[mf][nf] = MFMA16(af[mf], bf[nf], acc[mf][nf]);
    __builtin_amdgcn_s_setprio(0);
    // ---- phase B ----
    #pragma unroll
    for (int mf = 0; mf < 4; mf++) af[4+mf] = *(const h16x8*)(buf + abyte + 4096 + mf*1024);
    if (t < 30) stageB(t + 2);
    asm volatile("s_waitcnt lgkmcnt(0)" ::: "memory");
    __builtin_amdgcn_sched_barrier(0);
    __builtin_amdgcn_s_setprio(1);
    #pragma unroll
    for (int mf = 0; mf < 4; mf++)
      #pragma unroll
      for (int nf = 0; nf < 4; nf++)
        acc[4+mf][nf] = MFMA16(af[4+mf], bf[nf], acc[4+mf][nf]);
    __builtin_amdgcn_s_setprio(0);
    // ---- end-of-tile: tile t+1 landed in ALL waves, then barrier ----
    if (t < 30)       asm volatile("s_waitcnt vmcnt(4)" ::: "memory");
    else if (t == 30) asm volatile("s_waitcnt vmcnt(0)" ::: "memory");
    if (t < 31) {
      __builtin_amdgcn_sched_barrier(0);
      __builtin_amdgcn_s_barrier();
    }
  }
}

// ---------------- QKV GEMM (M=16384, N=3072, K=1024), natural-layout out ---
__global__ __launch_bounds__(512, 2) void k_qkv(
    const h16* __restrict__ xh, const h16* __restrict__ w3,
    h16* __restrict__ qn, h16* __restrict__ kn, h16* __restrict__ vn)
{
  extern __shared__ __align__(16) char smem[];   // 128 KiB
  const int tid = threadIdx.x;
  const int w = tid >> 6, l = tid & 63;
  const int m0 = blockIdx.x * 256;
  const int nt = blockIdx.y;                     // 0..11
  const int wr = w >> 2, wc = w & 3;

  f32x4 acc[8][4] = {};
  gemm256_loop(xh + (size_t)m0*1024, w3 + (size_t)(nt*256)*1024, smem, w, l, acc);

  const int proj = nt >> 2;   // 0=q 1=k 2=v (uniform per block)
  h16* dst = proj == 0 ? qn : (proj == 1 ? kn : vn);
  const int cb = (nt & 3)*256 + wc*64;
  #pragma unroll
  for (int mf = 0; mf < 8; mf++)
    #pragma unroll
    for (int nf = 0; nf < 4; nf++)
      #pragma unroll
      for (int r = 0; r < 4; r++) {
        int row = wr*128 + mf*16 + ((l >> 4) << 2) + r;
        int col = cb + nf*16 + (l & 15);
        dst[(size_t)(m0 + row)*1024 + col] = (h16)acc[mf][nf][r];
      }
}

// ---------------- final GEMM: out = An @ wo^T (M=16384, N=1024, K=1024) ---
__global__ __launch_bounds__(512, 2) void k_out(
    const h16* __restrict__ an, const h16* __restrict__ woh,
    float* __restrict__ out)
{
  extern __shared__ __align__(16) char smem[];
  const int tid = threadIdx.x;
  const int w = tid >> 6, l = tid & 63;
  const int m0 = blockIdx.x * 256;
  const int n0 = blockIdx.y * 256;
  const int wr = w >> 2, wc = w & 3;

  f32x4 acc[8][4] = {};
  gemm256_loop(an + (size_t)m0*1024, woh + (size_t)n0*1024, smem, w, l, acc);

  #pragma unroll
  for (int mf = 0; mf < 8; mf++)
    #pragma unroll
    for (int nf = 0; nf < 4; nf++)
      #pragma unroll
      for (int r = 0; r < 4; r++) {
        int row = wr*128 + mf*16 + ((l >> 4) << 2) + r;
        int col = n0 + wc*64 + nf*16 + (l & 15);
        out[(size_t)(m0 + row)*1024 + col] = acc[mf][nf][r];
      }
}

// ------- transpose from natural layout: K->RoPE->(K^T*k_dec), V->V^T ------
__global__ __launch_bounds__(256) void k_tr(
    const h16* __restrict__ kn, const h16* __restrict__ vn,
    const float* __restrict__ fc,
    h16* __restrict__ kts, h16* __restrict__ vt)
{
  __shared__ __align__(16) h16 tl[128*64];
  __shared__ float dt[128];
  const int tid = threadIdx.x;
  const int st = blockIdx.x;   // chunk 0..63
  const int bh = blockIdx.y;   // 0..31
  const int b = bh >> 4, h = bh & 15;
  if (tid < 128) {
    float slope = exp2f(-0.5f * (float)(h + 1));
    dt[tid] = expf(-slope * (float)(127 - tid));
  }
  const size_t ibase = ((size_t)(b*8192 + st*128))*1024 + h*64;
  const size_t obase = (size_t)bh*64*8192 + st*128;
  const int cr = tid >> 3, c8 = tid & 7;

  for (int which = 0; which < 2; ++which) {
    const h16* src = which ? vn : kn;
    h16* dstp = which ? vt : kts;
    __syncthreads();
    #pragma unroll
    for (int i = 0; i < 4; i++) {
      int r = i*32 + cr;
      h16x8 v = *(const h16x8*)(src + ibase + (size_t)r*1024 + c8*8);
      if (!which) v = rope8(v, fc + (size_t)(st*128 + r)*64 + c8*8);
      int slot = (c8 + ((r >> 3) & 7)) & 7;
      *(h16x8*)(tl + r*64 + slot*8) = v;
    }
    __syncthreads();
    #pragma unroll
    for (int i = 0; i < 4; i++) {
      int chunk = i*256 + tid;
      int d = chunk >> 4;
      int j8 = chunk & 15;
      h16x8 o;
      #pragma unroll
      for (int jj = 0; jj < 8; jj++) {
        int c = j8*8 + jj;
        int pos = (d + ((c >> 3) & 7)*8) & 63;
        float fv = (float)tl[c*64 + pos];
        if (!which) fv *= dt[c];
        o[jj] = (h16)fv;
      }
      *(h16x8*)(dstp + obase + (size_t)d*8192 + j8*8) = o;
    }
  }
}

// ---------------- per-chunk KV^T state ------------------------------------
__global__ __launch_bounds__(256) void k_kv(
    const h16* __restrict__ kts, const h16* __restrict__ vt,
    float* __restrict__ T)
{
  const int tid = threadIdx.x;
  const int t = blockIdx.x;
  const int bh = blockIdx.y;
  const int w = tid >> 6, l = tid & 63;
  const h16* vb = vt  + (size_t)bh*64*8192 + t*128;
  const h16* kb = kts + (size_t)bh*64*8192 + t*128;
  f32x4 acc[4] = {};
  h16x8 a[4];
  #pragma unroll
  for (int ks = 0; ks < 4; ks++)
    a[ks] = *(const h16x8*)(vb + (size_t)(w*16 + (l & 15))*8192 + ks*32 + (l >> 4)*8);
  #pragma unroll
  for (int nf = 0; nf < 4; nf++) {
    #pragma unroll
    for (int ks = 0; ks < 4; ks++) {
      h16x8 bfr = *(const h16x8*)(kb + (size_t)(nf*16 + (l & 15))*8192 + ks*32 + (l >> 4)*8);
      acc[nf] = MFMA16(a[ks], bfr, acc[nf]);
    }
  }
  float* Tb = T + ((size_t)bh*64 + t)*4096;
  #pragma unroll
  for (int nf = 0; nf < 4; nf++)
    #pragma unroll
    for (int r = 0; r < 4; r++) {
      int e = w*16 + ((l >> 4) << 2) + r;
      int d = nf*16 + (l & 15);
      Tb[e*64 + d] = acc[nf][r];
    }
}

// ---------------- decay prefix scan over chunks (1 elem/thread) -----------
__global__ __launch_bounds__(256) void k_scan(const float* __restrict__ T,
                                              h16* __restrict__ ph) {
  const int bh = blockIdx.x;
  const int j  = blockIdx.y * 256 + threadIdx.x;
  const int h = bh & 15;
  const float cdec = expf(-exp2f(-0.5f*(float)(h+1)) * 128.0f);
  const float* Tb = T + (size_t)bh*64*4096 + j;
  h16* pb = ph + (size_t)bh*64*4096 + j;
  float run = 0.f;
  for (int t = 0; t < 64; t++) {
    float kv = Tb[(size_t)t*4096];
    pb[(size_t)t*4096] = (h16)run;
    run = cdec*run + kv;
  }
}

// ------- per-chunk attention output (nat Q/K + on-the-fly RoPE) -----------
__global__ __launch_bounds__(256) void k_att(
    const h16* __restrict__ qn, const h16* __restrict__ kn,
    const float* __restrict__ fc,
    const h16* __restrict__ vt, const h16* __restrict__ ph,
    h16* __restrict__ oh)
{
  __shared__ __align__(16) h16 P[128*144];
  __shared__ float dt[128], qd[128];
  const int tid = threadIdx.x;
  const int t = blockIdx.x;
  const int bh = blockIdx.y;
  const int b = bh >> 4, h = bh & 15;
  if (tid < 128) {
    float slope = exp2f(-0.5f*(float)(h+1));
    dt[tid] = expf(-slope*(float)tid);
    qd[tid] = expf(-slope*(float)(tid+1));
  }
  __syncthreads();
  const int w = tid >> 6, l = tid & 63;
  const int iw = w * 32;
  const h16* qb = qn + ((size_t)(b*8192 + t*128))*1024 + h*64;
  const h16* kb = kn + ((size_t)(b*8192 + t*128))*1024 + h*64;
  const h16* vb = vt + (size_t)bh*64*8192 + t*128;
  const h16* pb = ph + ((size_t)bh*64 + t)*4096;
  const float* fcb = fc + (size_t)(t*128)*64;

  h16x8 aq[2][2];
  #pragma unroll
  for (int mf = 0; mf < 2; mf++)
    #pragma unroll
    for (int ks = 0; ks < 2; ks++) {
      int row = iw + mf*16 + (l & 15);
      int d0 = ks*32 + (l >> 4)*8;
      aq[mf][ks] = rope8(*(const h16x8*)(qb + (size_t)row*1024 + d0),
                         fcb + (size_t)row*64 + d0);
    }

  // QK^T — causal: tile (rows iw..iw+31) needs only cols j <= iw+31
  f32x4 sc[2][8] = {};
  #pragma unroll
  for (int nf = 0; nf < 8; nf++) {
    if (nf*16 <= iw + 31) {
      #pragma unroll
      for (int ks = 0; ks < 2; ks++) {
        int row = nf*16 + (l & 15);
        int d0 = ks*32 + (l >> 4)*8;
        h16x8 bk = rope8(*(const h16x8*)(kb + (size_t)row*1024 + d0),
                         fcb + (size_t)row*64 + d0);
        sc[0][nf] = MFMA16(aq[0][ks], bk, sc[0][nf]);
        sc[1][nf] = MFMA16(aq[1][ks], bk, sc[1][nf]);
      }
    }
  }
  #pragma unroll
  for (int mf = 0; mf < 2; mf++) {
    #pragma unroll
    for (int nf = 0; nf < 8; nf++) {
      #pragma unroll
      for (int r = 0; r < 4; r++) {
        int i = iw + mf*16 + ((l >> 4) << 2) + r;
        int j = nf*16 + (l & 15);
        int diff = i - j;
        float v = diff >= 0 ? sc[mf][nf][r]*dt[diff] : 0.f;
        P[i*144 + j] = (h16)v;
      }
    }
  }
  f32x4 ao[2][4] = {};
  #pragma unroll
  for (int kc = 0; kc < 4; kc++) {
    h16x8 ap0 = *(const h16x8*)(P + (size_t)(iw + (l & 15))*144 + kc*32 + (l >> 4)*8);
    h16x8 ap1 = *(const h16x8*)(P + (size_t)(iw + 16 + (l & 15))*144 + kc*32 + (l >> 4)*8);
    #pragma unroll
    for (int nf = 0; nf < 4; nf++) {
      h16x8 bv = *(const h16x8*)(vb + (size_t)(nf*16 + (l & 15))*8192 + kc*32 + (l >> 4)*8);
      ao[0][nf] = MFMA16(ap0, bv, ao[0][nf]);
      ao[1][nf] = MFMA16(ap1, bv, ao[1][nf]);
    }
  }
  f32x4 a2[2][4] = {};
  #pragma unroll
  for (int ks = 0; ks < 2; ks++) {
    #pragma unroll
    for (int nf = 0; nf < 4; nf++) {
      h16x8 bs = *(const h16x8*)(pb + (size_t)(nf*16 + (l & 15))*64 + ks*32 + (l >> 4)*8);
      a2[0][nf] = MFMA16(aq[0][ks], bs, a2[0][nf]);
      a2[1][nf] = MFMA16(aq[1][ks], bs, a2[1][nf]);
    }
  }
  #pragma unroll
  for (int mf = 0; mf < 2; mf++) {
    #pragma unroll
    for (int nf = 0; nf < 4; nf++) {
      #pragma unroll
      for (int r = 0; r < 4; r++) {
        int i = iw + mf*16 + ((l >> 4) << 2) + r;
        int e = nf*16 + (l & 15);
        float o = ao[mf][nf][r] + qd[i]*a2[mf][nf][r];
        int s = t*128 + i;
        oh[((size_t)(b*8192 + s))*1024 + h*64 + e] = (h16)o;
      }
    }
  }
}

// ---------------- RMSNorm (per token, fp16 in) -> fp16 --------------------
__global__ __launch_bounds__(256) void k_rms(const h16* __restrict__ o,
                                             const float* __restrict__ rw,
                                             h16* __restrict__ an) {
  const int tid = threadIdx.x;
  const size_t base = (size_t)blockIdx.x * 1024;
  h16x4 hv = *(const h16x4*)(o + base + tid*4);
  float v0 = (float)hv[0], v1 = (float)hv[1], v2 = (float)hv[2], v3 = (float)hv[3];
  float ss = v0*v0 + v1*v1 + v2*v2 + v3*v3;
  #pragma unroll
  for (int off = 32; off > 0; off >>= 1) ss += __shfl_down(ss, off);
  __shared__ float red[4];
  if ((tid & 63) == 0) red[tid >> 6] = ss;
  __syncthreads();
  float f = rsqrtf((red[0]+red[1]+red[2]+red[3]) * (1.0f/1024.0f) + 1e-5f);
  float4 wv = *(const float4*)(rw + tid*4);
  h16x4 r;
  r[0] = (h16)(v0*f*wv.x); r[1] = (h16)(v1*f*wv.y);
  r[2] = (h16)(v2*f*wv.z); r[3] = (h16)(v3*f*wv.w);
  *(h16x4*)(an + base + tid*4) = r;
}

// --------------------------------------------------------------------------
extern "C" void kernel_launch(void* const* d_in, const int* in_sizes, int n_in,
                              void* d_out, int out_size, void* d_ws, size_t ws_size,
                              hipStream_t stream) {
  const float* x  = (const float*)d_in[0];
  const float* fc = (const float*)d_in[1];
  const float* wq = (const float*)d_in[2];
  const float* wk = (const float*)d_in[3];
  const float* wv = (const float*)d_in[4];
  const float* wo = (const float*)d_in[5];
  const float* rw = (const float*)d_in[6];
  float* out = (float*)d_out;

  char* p = (char*)d_ws;
  const size_t SZ = 33554432;
  h16* xh  = (h16*)(p);                  // later reused for An
  h16* vn  = (h16*)(p + 3*SZ);           // V natural; later reused for Ph
  h16* kts = (h16*)(p + 4*SZ);
  h16* vt  = (h16*)(p + 5*SZ);
  float* T = (float*)(p + 6*SZ);         // later reused for O (fp16)
  h16* w3  = (h16*)(p + 7*SZ);
  h16* woh = (h16*)(p + 7*SZ + 6291456);
  // Q/K natural layout live in d_out (free until k_out overwrites it)
  h16* qn = (h16*)out;
  h16* kn = (h16*)out + 16777216;

  (void)hipFuncSetAttribute((const void*)k_qkv, hipFuncAttributeMaxDynamicSharedMemorySize, 131072);
  (void)hipFuncSetAttribute((const void*)k_out, hipFuncAttributeMaxDynamicSharedMemorySize, 131072);

  hipLaunchKernelGGL(k_cvt, dim3(8192), dim3(256), 0, stream, x, xh, 16777216);
  hipLaunchKernelGGL(k_cvt, dim3(512), dim3(256), 0, stream, wq, w3, 1048576);
  hipLaunchKernelGGL(k_cvt, dim3(512), dim3(256), 0, stream, wk, w3 + 1048576, 1048576);
  hipLaunchKernelGGL(k_cvt, dim3(512), dim3(256), 0, stream, wv, w3 + 2097152, 1048576);
  hipLaunchKernelGGL(k_cvt, dim3(512), dim3(256), 0, stream, wo, woh, 1048576);

  hipLaunchKernelGGL(k_qkv, dim3(64, 12), dim3(512), 131072, stream, xh, w3, qn, kn, vn);
  hipLaunchKernelGGL(k_tr,  dim3(64, 32), dim3(256), 0, stream, kn, vn, fc, kts, vt);
  hipLaunchKernelGGL(k_kv,  dim3(64, 32), dim3(256), 0, stream, kts, vt, T);
  h16* ph = vn;  // vn dead after k_tr
  hipLaunchKernelGGL(k_scan, dim3(32, 16), dim3(256), 0, stream, T, ph);
  h16* oh = (h16*)T;  // T dead after k_scan
  hipLaunchKernelGGL(k_att, dim3(64, 32), dim3(256), 0, stream, qn, kn, fc, vt, ph, oh);
  h16* an = xh;  // xh dead after k_qkv
  hipLaunchKernelGGL(k_rms, dim3(16384), dim3(256), 0, stream, oh, rw, an);
  hipLaunchKernelGGL(k_out, dim3(64, 4), dim3(512), 131072, stream, an, woh, out);
}

// Round 10
// 295.464 us; speedup vs baseline: 1.1068x; 1.1068x over previous
//
#include <hip/hip_runtime.h>

// B=2 S=8192 E=1024 H=16 D=64 CHUNK=128 NC=64

using h16   = _Float16;
using h16x8 = __attribute__((ext_vector_type(8))) _Float16;
using h16x4 = __attribute__((ext_vector_type(4))) _Float16;
using f32x4 = __attribute__((ext_vector_type(4))) float;

#define MFMA16(a,b,c) __builtin_amdgcn_mfma_f32_16x16x32_f16(a,b,c,0,0,0)

#define GLOAD16(gp, lp) __builtin_amdgcn_global_load_lds( \
    (const __attribute__((address_space(1))) void*)(gp),  \
    (__attribute__((address_space(3))) void*)(lp), 16, 0, 0)

// RoPE on 8 contiguous dims starting at even d0: fp = fc + s*64 + d0.
__device__ __forceinline__ h16x8 rope8(h16x8 v, const float* __restrict__ fp) {
  float4 f0 = *(const float4*)fp;
  float4 f1 = *(const float4*)(fp + 4);
  h16x8 o; float x0, x1;
  x0=(float)v[0]; x1=(float)v[1]; o[0]=(h16)(x0*f0.x - x1*f0.y); o[1]=(h16)(x1*f0.x + x0*f0.y);
  x0=(float)v[2]; x1=(float)v[3]; o[2]=(h16)(x0*f0.z - x1*f0.w); o[3]=(h16)(x1*f0.z + x0*f0.w);
  x0=(float)v[4]; x1=(float)v[5]; o[4]=(h16)(x0*f1.x - x1*f1.y); o[5]=(h16)(x1*f1.x + x0*f1.y);
  x0=(float)v[6]; x1=(float)v[7]; o[6]=(h16)(x0*f1.z - x1*f1.w); o[7]=(h16)(x1*f1.z + x0*f1.w);
  return o;
}

// ---------------- fp32 -> fp16 convert (8 elems/thread) ----------------
__global__ __launch_bounds__(256) void k_cvt(const float* __restrict__ s,
                                             h16* __restrict__ d, int n) {
  int i = (blockIdx.x * 256 + threadIdx.x) * 8;
  if (i >= n) return;
  float4 a = *(const float4*)(s + i);
  float4 b = *(const float4*)(s + i + 4);
  h16x8 o;
  o[0]=(h16)a.x; o[1]=(h16)a.y; o[2]=(h16)a.z; o[3]=(h16)a.w;
  o[4]=(h16)b.x; o[5]=(h16)b.y; o[6]=(h16)b.z; o[7]=(h16)b.w;
  *(h16x8*)(d + i) = o;
}

// 4 weight matrices (1M elems each) in one launch; blockIdx.y selects.
__global__ __launch_bounds__(256) void k_cvt4(
    const float* __restrict__ s0, const float* __restrict__ s1,
    const float* __restrict__ s2, const float* __restrict__ s3,
    h16* __restrict__ d0, h16* __restrict__ d1,
    h16* __restrict__ d2, h16* __restrict__ d3) {
  const float* s = blockIdx.y == 0 ? s0 : (blockIdx.y == 1 ? s1 : (blockIdx.y == 2 ? s2 : s3));
  h16* d        = blockIdx.y == 0 ? d0 : (blockIdx.y == 1 ? d1 : (blockIdx.y == 2 ? d2 : d3));
  int i = (blockIdx.x * 256 + threadIdx.x) * 8;
  float4 a = *(const float4*)(s + i);
  float4 b = *(const float4*)(s + i + 4);
  h16x8 o;
  o[0]=(h16)a.x; o[1]=(h16)a.y; o[2]=(h16)a.z; o[3]=(h16)a.w;
  o[4]=(h16)b.x; o[5]=(h16)b.y; o[6]=(h16)b.z; o[7]=(h16)b.w;
  *(h16x8*)(d + i) = o;
}

// ===== 256x256 GEMM mainloop: BK=32, 4-deep ring, phase-split (r9-proven) ==
__device__ __forceinline__ void gemm256_loop(
    const h16* __restrict__ At, const h16* __restrict__ Bt,
    char* smem, int w, int l, f32x4 (&acc)[8][4])
{
  const int tid = w*64 + l;
  const int wr = w >> 2, wc = w & 3;

  size_t gof[2];
  #pragma unroll
  for (int c = 0; c < 2; c++) {
    int G = c*512 + tid;
    int pp = G >> 3;
    int idx = (G & 7) ^ (pp & 7);
    gof[c] = (size_t)(2*pp + (idx >> 2))*1024 + (idx & 3)*8;
  }

  const int q16 = ((((l & 1) << 2) | (l >> 4)) ^ ((l >> 1) & 7)) * 16;
  const int abyte = wr*8192 + ((l >> 1) & 7)*128 + q16;
  const int bbyte = 16384 + wc*4096 + ((l >> 1) & 7)*128 + q16;

  auto stageA = [&](int kt) {
    char* buf = smem + (kt & 3)*32768;
    #pragma unroll
    for (int c = 0; c < 2; c++)
      GLOAD16(At + gof[c] + kt*32, buf + c*8192 + w*1024);
  };
  auto stageB = [&](int kt) {
    char* buf = smem + (kt & 3)*32768;
    #pragma unroll
    for (int c = 0; c < 2; c++)
      GLOAD16(Bt + gof[c] + kt*32, buf + 16384 + c*8192 + w*1024);
  };

  stageA(0); stageB(0); stageA(1); stageB(1);
  asm volatile("s_waitcnt vmcnt(4)" ::: "memory");
  __builtin_amdgcn_sched_barrier(0);
  __builtin_amdgcn_s_barrier();

  for (int t = 0; t < 32; ++t) {
    const char* buf = smem + (t & 3)*32768;
    h16x8 af[8], bf[4];
    #pragma unroll
    for (int mf = 0; mf < 4; mf++) af[mf] = *(const h16x8*)(buf + abyte + mf*1024);
    #pragma unroll
    for (int nf = 0; nf < 4; nf++) bf[nf] = *(const h16x8*)(buf + bbyte + nf*1024);
    if (t < 30) stageA(t + 2);
    asm volatile("s_waitcnt lgkmcnt(0)" ::: "memory");
    __builtin_amdgcn_sched_barrier(0);
    __builtin_amdgcn_s_setprio(1);
    #pragma unroll
    for (int mf = 0; mf < 4; mf++)
      #pragma unroll
      for (int nf = 0; nf < 4; nf++)
        acc[mf][nf] = MFMA16(af[mf], bf[nf], acc[mf][nf]);
    __builtin_amdgcn_s_setprio(0);
    #pragma unroll
    for (int mf = 0; mf < 4; mf++) af[4+mf] = *(const h16x8*)(buf + abyte + 4096 + mf*1024);
    if (t < 30) stageB(t + 2);
    asm volatile("s_waitcnt lgkmcnt(0)" ::: "memory");
    __builtin_amdgcn_sched_barrier(0);
    __builtin_amdgcn_s_setprio(1);
    #pragma unroll
    for (int mf = 0; mf < 4; mf++)
      #pragma unroll
      for (int nf = 0; nf < 4; nf++)
        acc[4+mf][nf] = MFMA16(af[4+mf], bf[nf], acc[4+mf][nf]);
    __builtin_amdgcn_s_setprio(0);
    if (t < 30)       asm volatile("s_waitcnt vmcnt(4)" ::: "memory");
    else if (t == 30) asm volatile("s_waitcnt vmcnt(0)" ::: "memory");
    if (t < 31) {
      __builtin_amdgcn_sched_barrier(0);
      __builtin_amdgcn_s_barrier();
    }
  }
}

// ---------------- QKV GEMM (M=16384, N=3072, K=1024), natural-layout out ---
__global__ __launch_bounds__(512, 2) void k_qkv(
    const h16* __restrict__ xh, const h16* __restrict__ w3,
    h16* __restrict__ qn, h16* __restrict__ kn, h16* __restrict__ vn)
{
  extern __shared__ __align__(16) char smem[];   // 128 KiB
  const int tid = threadIdx.x;
  const int w = tid >> 6, l = tid & 63;
  const int m0 = blockIdx.x * 256;
  const int nt = blockIdx.y;                     // 0..11
  const int wr = w >> 2, wc = w & 3;

  f32x4 acc[8][4] = {};
  gemm256_loop(xh + (size_t)m0*1024, w3 + (size_t)(nt*256)*1024, smem, w, l, acc);

  const int proj = nt >> 2;   // 0=q 1=k 2=v (uniform per block)
  h16* dst = proj == 0 ? qn : (proj == 1 ? kn : vn);
  const int cb = (nt & 3)*256 + wc*64;
  #pragma unroll
  for (int mf = 0; mf < 8; mf++)
    #pragma unroll
    for (int nf = 0; nf < 4; nf++)
      #pragma unroll
      for (int r = 0; r < 4; r++) {
        int row = wr*128 + mf*16 + ((l >> 4) << 2) + r;
        int col = cb + nf*16 + (l & 15);
        dst[(size_t)(m0 + row)*1024 + col] = (h16)acc[mf][nf][r];
      }
}

// ---------------- final GEMM: out = An @ wo^T (M=16384, N=1024, K=1024) ---
__global__ __launch_bounds__(512, 2) void k_out(
    const h16* __restrict__ an, const h16* __restrict__ woh,
    float* __restrict__ out)
{
  extern __shared__ __align__(16) char smem[];
  const int tid = threadIdx.x;
  const int w = tid >> 6, l = tid & 63;
  const int m0 = blockIdx.x * 256;
  const int n0 = blockIdx.y * 256;
  const int wr = w >> 2, wc = w & 3;

  f32x4 acc[8][4] = {};
  gemm256_loop(an + (size_t)m0*1024, woh + (size_t)n0*1024, smem, w, l, acc);

  #pragma unroll
  for (int mf = 0; mf < 8; mf++)
    #pragma unroll
    for (int nf = 0; nf < 4; nf++)
      #pragma unroll
      for (int r = 0; r < 4; r++) {
        int row = wr*128 + mf*16 + ((l >> 4) << 2) + r;
        int col = n0 + wc*64 + nf*16 + (l & 15);
        out[(size_t)(m0 + row)*1024 + col] = acc[mf][nf][r];
      }
}

// ===== fused transpose + per-chunk KV state ================================
// Per (chunk st, bh): K-nat -> rope -> K^T*k_dec (LDS only, never global);
// V-nat -> V^T (LDS + global vt); then T[e][d] = sum_c V^T[e][c]*Ks^T[d][c]
// via 16 MFMA/wave, written fp16. Padded LDS stride 136 h16 (272B: 16B-aligned,
// 2-way banks max).
__global__ __launch_bounds__(256) void k_trkv(
    const h16* __restrict__ kn, const h16* __restrict__ vn,
    const float* __restrict__ fc,
    h16* __restrict__ vt, h16* __restrict__ Th)
{
  __shared__ __align__(16) h16 tl[128*64];     // row-major staging
  __shared__ __align__(16) h16 kT2[64*136];    // Ks^T (d, c) padded
  __shared__ __align__(16) h16 vT2[64*136];    // V^T  (e, c) padded
  __shared__ float dt[128];
  const int tid = threadIdx.x;
  const int st = blockIdx.x;   // chunk 0..63
  const int bh = blockIdx.y;   // 0..31
  const int b = bh >> 4, h = bh & 15;
  if (tid < 128) {
    float slope = exp2f(-0.5f * (float)(h + 1));
    dt[tid] = expf(-slope * (float)(127 - tid));
  }
  const size_t ibase = ((size_t)(b*8192 + st*128))*1024 + h*64;
  const size_t obase = (size_t)bh*64*8192 + st*128;
  const int cr = tid >> 3, c8 = tid & 7;

  for (int which = 0; which < 2; ++which) {
    const h16* src = which ? vn : kn;
    h16* dT2 = which ? vT2 : kT2;
    __syncthreads();                       // tl free (or first pass)
    #pragma unroll
    for (int i = 0; i < 4; i++) {
      int r = i*32 + cr;
      h16x8 v = *(const h16x8*)(src + ibase + (size_t)r*1024 + c8*8);
      if (!which) v = rope8(v, fc + (size_t)(st*128 + r)*64 + c8*8);
      int slot = (c8 + ((r >> 3) & 7)) & 7;
      *(h16x8*)(tl + r*64 + slot*8) = v;
    }
    __syncthreads();
    #pragma unroll
    for (int i = 0; i < 4; i++) {
      int chunk = i*256 + tid;
      int d = chunk >> 4;
      int j8 = chunk & 15;
      h16x8 o;
      #pragma unroll
      for (int jj = 0; jj < 8; jj++) {
        int c = j8*8 + jj;
        int pos = (d + ((c >> 3) & 7)*8) & 63;
        float fv = (float)tl[c*64 + pos];
        if (!which) fv *= dt[c];
        o[jj] = (h16)fv;
      }
      *(h16x8*)(dT2 + d*136 + j8*8) = o;
      if (which) *(h16x8*)(vt + obase + (size_t)d*8192 + j8*8) = o;
    }
  }
  __syncthreads();                         // kT2 + vT2 ready

  // T = V^T x Ks^T^T : per wave e-range 16, all 64 d
  const int w = tid >> 6, l = tid & 63;
  f32x4 acc[4] = {};
  h16x8 a[4];
  #pragma unroll
  for (int ks = 0; ks < 4; ks++)
    a[ks] = *(const h16x8*)(vT2 + (w*16 + (l & 15))*136 + ks*32 + (l >> 4)*8);
  #pragma unroll
  for (int nf = 0; nf < 4; nf++) {
    #pragma unroll
    for (int ks = 0; ks < 4; ks++) {
      h16x8 bfr = *(const h16x8*)(kT2 + (nf*16 + (l & 15))*136 + ks*32 + (l >> 4)*8);
      acc[nf] = MFMA16(a[ks], bfr, acc[nf]);
    }
  }
  h16* Tb = Th + ((size_t)bh*64 + st)*4096;
  #pragma unroll
  for (int nf = 0; nf < 4; nf++)
    #pragma unroll
    for (int r = 0; r < 4; r++) {
      int e = w*16 + ((l >> 4) << 2) + r;
      int d = nf*16 + (l & 15);
      Tb[e*64 + d] = (h16)acc[nf][r];
    }
}

// ---------------- decay prefix scan over chunks (1 elem/thread, fp16 T) ---
__global__ __launch_bounds__(256) void k_scan(const h16* __restrict__ Th,
                                              h16* __restrict__ ph) {
  const int bh = blockIdx.x;
  const int j  = blockIdx.y * 256 + threadIdx.x;
  const int h = bh & 15;
  const float cdec = expf(-exp2f(-0.5f*(float)(h+1)) * 128.0f);
  const h16* Tb = Th + (size_t)bh*64*4096 + j;
  h16* pb = ph + (size_t)bh*64*4096 + j;
  float run = 0.f;
  for (int t = 0; t < 64; t++) {
    float kv = (float)Tb[(size_t)t*4096];
    pb[(size_t)t*4096] = (h16)run;
    run = cdec*run + kv;
  }
}

// ------- per-chunk attention output (nat Q/K + on-the-fly RoPE) -----------
__global__ __launch_bounds__(256) void k_att(
    const h16* __restrict__ qn, const h16* __restrict__ kn,
    const float* __restrict__ fc,
    const h16* __restrict__ vt, const h16* __restrict__ ph,
    h16* __restrict__ oh)
{
  __shared__ __align__(16) h16 P[128*144];
  __shared__ float dt[128], qd[128];
  const int tid = threadIdx.x;
  const int t = blockIdx.x;
  const int bh = blockIdx.y;
  const int b = bh >> 4, h = bh & 15;
  if (tid < 128) {
    float slope = exp2f(-0.5f*(float)(h+1));
    dt[tid] = expf(-slope*(float)tid);
    qd[tid] = expf(-slope*(float)(tid+1));
  }
  __syncthreads();
  const int w = tid >> 6, l = tid & 63;
  const int iw = w * 32;
  const h16* qb = qn + ((size_t)(b*8192 + t*128))*1024 + h*64;
  const h16* kb = kn + ((size_t)(b*8192 + t*128))*1024 + h*64;
  const h16* vb = vt + (size_t)bh*64*8192 + t*128;
  const h16* pb = ph + ((size_t)bh*64 + t)*4096;
  const float* fcb = fc + (size_t)(t*128)*64;

  h16x8 aq[2][2];
  #pragma unroll
  for (int mf = 0; mf < 2; mf++)
    #pragma unroll
    for (int ks = 0; ks < 2; ks++) {
      int row = iw + mf*16 + (l & 15);
      int d0 = ks*32 + (l >> 4)*8;
      aq[mf][ks] = rope8(*(const h16x8*)(qb + (size_t)row*1024 + d0),
                         fcb + (size_t)row*64 + d0);
    }

  // QK^T — causal: tile (rows iw..iw+31) needs only cols j <= iw+31
  f32x4 sc[2][8] = {};
  #pragma unroll
  for (int nf = 0; nf < 8; nf++) {
    if (nf*16 <= iw + 31) {
      #pragma unroll
      for (int ks = 0; ks < 2; ks++) {
        int row = nf*16 + (l & 15);
        int d0 = ks*32 + (l >> 4)*8;
        h16x8 bk = rope8(*(const h16x8*)(kb + (size_t)row*1024 + d0),
                         fcb + (size_t)row*64 + d0);
        sc[0][nf] = MFMA16(aq[0][ks], bk, sc[0][nf]);
        sc[1][nf] = MFMA16(aq[1][ks], bk, sc[1][nf]);
      }
    }
  }
  #pragma unroll
  for (int mf = 0; mf < 2; mf++) {
    #pragma unroll
    for (int nf = 0; nf < 8; nf++) {
      #pragma unroll
      for (int r = 0; r < 4; r++) {
        int i = iw + mf*16 + ((l >> 4) << 2) + r;
        int j = nf*16 + (l & 15);
        int diff = i - j;
        float v = diff >= 0 ? sc[mf][nf][r]*dt[diff] : 0.f;
        P[i*144 + j] = (h16)v;
      }
    }
  }
  f32x4 ao[2][4] = {};
  #pragma unroll
  for (int kc = 0; kc < 4; kc++) {
    h16x8 ap0 = *(const h16x8*)(P + (size_t)(iw + (l & 15))*144 + kc*32 + (l >> 4)*8);
    h16x8 ap1 = *(const h16x8*)(P + (size_t)(iw + 16 + (l & 15))*144 + kc*32 + (l >> 4)*8);
    #pragma unroll
    for (int nf = 0; nf < 4; nf++) {
      h16x8 bv = *(const h16x8*)(vb + (size_t)(nf*16 + (l & 15))*8192 + kc*32 + (l >> 4)*8);
      ao[0][nf] = MFMA16(ap0, bv, ao[0][nf]);
      ao[1][nf] = MFMA16(ap1, bv, ao[1][nf]);
    }
  }
  f32x4 a2[2][4] = {};
  #pragma unroll
  for (int ks = 0; ks < 2; ks++) {
    #pragma unroll
    for (int nf = 0; nf < 4; nf++) {
      h16x8 bs = *(const h16x8*)(pb + (size_t)(nf*16 + (l & 15))*64 + ks*32 + (l >> 4)*8);
      a2[0][nf] = MFMA16(aq[0][ks], bs, a2[0][nf]);
      a2[1][nf] = MFMA16(aq[1][ks], bs, a2[1][nf]);
    }
  }
  #pragma unroll
  for (int mf = 0; mf < 2; mf++) {
    #pragma unroll
    for (int nf = 0; nf < 4; nf++) {
      #pragma unroll
      for (int r = 0; r < 4; r++) {
        int i = iw + mf*16 + ((l >> 4) << 2) + r;
        int e = nf*16 + (l & 15);
        float o = ao[mf][nf][r] + qd[i]*a2[mf][nf][r];
        int s = t*128 + i;
        oh[((size_t)(b*8192 + s))*1024 + h*64 + e] = (h16)o;
      }
    }
  }
}

// ---------------- RMSNorm (per token, fp16 in) -> fp16 --------------------
__global__ __launch_bounds__(256) void k_rms(const h16* __restrict__ o,
                                             const float* __restrict__ rw,
                                             h16* __restrict__ an) {
  const int tid = threadIdx.x;
  const size_t base = (size_t)blockIdx.x * 1024;
  h16x4 hv = *(const h16x4*)(o + base + tid*4);
  float v0 = (float)hv[0], v1 = (float)hv[1], v2 = (float)hv[2], v3 = (float)hv[3];
  float ss = v0*v0 + v1*v1 + v2*v2 + v3*v3;
  #pragma unroll
  for (int off = 32; off > 0; off >>= 1) ss += __shfl_down(ss, off);
  __shared__ float red[4];
  if ((tid & 63) == 0) red[tid >> 6] = ss;
  __syncthreads();
  float f = rsqrtf((red[0]+red[1]+red[2]+red[3]) * (1.0f/1024.0f) + 1e-5f);
  float4 wv = *(const float4*)(rw + tid*4);
  h16x4 r;
  r[0] = (h16)(v0*f*wv.x); r[1] = (h16)(v1*f*wv.y);
  r[2] = (h16)(v2*f*wv.z); r[3] = (h16)(v3*f*wv.w);
  *(h16x4*)(an + base + tid*4) = r;
}

// --------------------------------------------------------------------------
extern "C" void kernel_launch(void* const* d_in, const int* in_sizes, int n_in,
                              void* d_out, int out_size, void* d_ws, size_t ws_size,
                              hipStream_t stream) {
  const float* x  = (const float*)d_in[0];
  const float* fc = (const float*)d_in[1];
  const float* wq = (const float*)d_in[2];
  const float* wk = (const float*)d_in[3];
  const float* wv = (const float*)d_in[4];
  const float* wo = (const float*)d_in[5];
  const float* rw = (const float*)d_in[6];
  float* out = (float*)d_out;

  char* p = (char*)d_ws;
  const size_t SZ = 33554432;
  h16* xh  = (h16*)(p);                  // later reused for An
  h16* vn  = (h16*)(p + 3*SZ);           // V natural; later reused for Ph
  h16* Th  = (h16*)(p + 4*SZ);           // fp16 per-chunk KV states (17 MB)
  h16* vt  = (h16*)(p + 5*SZ);
  h16* oh  = (h16*)(p + 6*SZ);           // O fp16
  h16* w3  = (h16*)(p + 7*SZ);
  h16* woh = (h16*)(p + 7*SZ + 6291456);
  // Q/K natural layout live in d_out (free until k_out overwrites it)
  h16* qn = (h16*)out;
  h16* kn = (h16*)out + 16777216;

  (void)hipFuncSetAttribute((const void*)k_qkv, hipFuncAttributeMaxDynamicSharedMemorySize, 131072);
  (void)hipFuncSetAttribute((const void*)k_out, hipFuncAttributeMaxDynamicSharedMemorySize, 131072);

  hipLaunchKernelGGL(k_cvt, dim3(8192), dim3(256), 0, stream, x, xh, 16777216);
  hipLaunchKernelGGL(k_cvt4, dim3(512, 4), dim3(256), 0, stream,
                     wq, wk, wv, wo, w3, w3 + 1048576, w3 + 2097152, woh);

  hipLaunchKernelGGL(k_qkv, dim3(64, 12), dim3(512), 131072, stream, xh, w3, qn, kn, vn);
  hipLaunchKernelGGL(k_trkv, dim3(64, 32), dim3(256), 0, stream, kn, vn, fc, vt, Th);
  h16* ph = vn;  // vn dead after k_trkv
  hipLaunchKernelGGL(k_scan, dim3(32, 16), dim3(256), 0, stream, Th, ph);
  hipLaunchKernelGGL(k_att, dim3(64, 32), dim3(256), 0, stream, qn, kn, fc, vt, ph, oh);
  h16* an = xh;  // xh dead after k_qkv
  hipLaunchKernelGGL(k_rms, dim3(16384), dim3(256), 0, stream, oh, rw, an);
  hipLaunchKernelGGL(k_out, dim3(64, 4), dim3(512), 131072, stream, an, woh, out);
}

// Round 11
// 293.648 us; speedup vs baseline: 1.1136x; 1.0062x over previous
//
#include <hip/hip_runtime.h>

// B=2 S=8192 E=1024 H=16 D=64 CHUNK=128 NC=64

using h16   = _Float16;
using h16x8 = __attribute__((ext_vector_type(8))) _Float16;
using h16x4 = __attribute__((ext_vector_type(4))) _Float16;
using f32x4 = __attribute__((ext_vector_type(4))) float;

#define MFMA16(a,b,c) __builtin_amdgcn_mfma_f32_16x16x32_f16(a,b,c,0,0,0)

#define GLOAD16(gp, lp) __builtin_amdgcn_global_load_lds( \
    (const __attribute__((address_space(1))) void*)(gp),  \
    (__attribute__((address_space(3))) void*)(lp), 16, 0, 0)

// RoPE on 8 contiguous dims starting at even d0: fp = fc + s*64 + d0.
__device__ __forceinline__ h16x8 rope8(h16x8 v, const float* __restrict__ fp) {
  float4 f0 = *(const float4*)fp;
  float4 f1 = *(const float4*)(fp + 4);
  h16x8 o; float x0, x1;
  x0=(float)v[0]; x1=(float)v[1]; o[0]=(h16)(x0*f0.x - x1*f0.y); o[1]=(h16)(x1*f0.x + x0*f0.y);
  x0=(float)v[2]; x1=(float)v[3]; o[2]=(h16)(x0*f0.z - x1*f0.w); o[3]=(h16)(x1*f0.z + x0*f0.w);
  x0=(float)v[4]; x1=(float)v[5]; o[4]=(h16)(x0*f1.x - x1*f1.y); o[5]=(h16)(x1*f1.x + x0*f1.y);
  x0=(float)v[6]; x1=(float)v[7]; o[6]=(h16)(x0*f1.z - x1*f1.w); o[7]=(h16)(x1*f1.z + x0*f1.w);
  return o;
}

// ---------------- fp32 -> fp16 convert (8 elems/thread) ----------------
__global__ __launch_bounds__(256) void k_cvt(const float* __restrict__ s,
                                             h16* __restrict__ d, int n) {
  int i = (blockIdx.x * 256 + threadIdx.x) * 8;
  if (i >= n) return;
  float4 a = *(const float4*)(s + i);
  float4 b = *(const float4*)(s + i + 4);
  h16x8 o;
  o[0]=(h16)a.x; o[1]=(h16)a.y; o[2]=(h16)a.z; o[3]=(h16)a.w;
  o[4]=(h16)b.x; o[5]=(h16)b.y; o[6]=(h16)b.z; o[7]=(h16)b.w;
  *(h16x8*)(d + i) = o;
}

// 4 weight matrices in one launch; wo gets rms_w folded into its columns.
__global__ __launch_bounds__(256) void k_cvt4(
    const float* __restrict__ s0, const float* __restrict__ s1,
    const float* __restrict__ s2, const float* __restrict__ s3,
    const float* __restrict__ rw,
    h16* __restrict__ d0, h16* __restrict__ d1,
    h16* __restrict__ d2, h16* __restrict__ d3) {
  const float* s = blockIdx.y == 0 ? s0 : (blockIdx.y == 1 ? s1 : (blockIdx.y == 2 ? s2 : s3));
  h16* d        = blockIdx.y == 0 ? d0 : (blockIdx.y == 1 ? d1 : (blockIdx.y == 2 ? d2 : d3));
  int i = (blockIdx.x * 256 + threadIdx.x) * 8;
  float4 a = *(const float4*)(s + i);
  float4 b = *(const float4*)(s + i + 4);
  if (blockIdx.y == 3) {   // wo: fold rms weight per column (k = i mod 1024)
    const float* rp = rw + (i & 1023);
    float4 r0 = *(const float4*)rp;
    float4 r1 = *(const float4*)(rp + 4);
    a.x*=r0.x; a.y*=r0.y; a.z*=r0.z; a.w*=r0.w;
    b.x*=r1.x; b.y*=r1.y; b.z*=r1.z; b.w*=r1.w;
  }
  h16x8 o;
  o[0]=(h16)a.x; o[1]=(h16)a.y; o[2]=(h16)a.z; o[3]=(h16)a.w;
  o[4]=(h16)b.x; o[5]=(h16)b.y; o[6]=(h16)b.z; o[7]=(h16)b.w;
  *(h16x8*)(d + i) = o;
}

// ===== 256x256 GEMM mainloop: BK=32, 4-deep ring, phase-split (r9-proven) ==
__device__ __forceinline__ void gemm256_loop(
    const h16* __restrict__ At, const h16* __restrict__ Bt,
    char* smem, int w, int l, f32x4 (&acc)[8][4])
{
  const int tid = w*64 + l;
  const int wr = w >> 2, wc = w & 3;

  size_t gof[2];
  #pragma unroll
  for (int c = 0; c < 2; c++) {
    int G = c*512 + tid;
    int pp = G >> 3;
    int idx = (G & 7) ^ (pp & 7);
    gof[c] = (size_t)(2*pp + (idx >> 2))*1024 + (idx & 3)*8;
  }

  const int q16 = ((((l & 1) << 2) | (l >> 4)) ^ ((l >> 1) & 7)) * 16;
  const int abyte = wr*8192 + ((l >> 1) & 7)*128 + q16;
  const int bbyte = 16384 + wc*4096 + ((l >> 1) & 7)*128 + q16;

  auto stageA = [&](int kt) {
    char* buf = smem + (kt & 3)*32768;
    #pragma unroll
    for (int c = 0; c < 2; c++)
      GLOAD16(At + gof[c] + kt*32, buf + c*8192 + w*1024);
  };
  auto stageB = [&](int kt) {
    char* buf = smem + (kt & 3)*32768;
    #pragma unroll
    for (int c = 0; c < 2; c++)
      GLOAD16(Bt + gof[c] + kt*32, buf + 16384 + c*8192 + w*1024);
  };

  stageA(0); stageB(0); stageA(1); stageB(1);
  asm volatile("s_waitcnt vmcnt(4)" ::: "memory");
  __builtin_amdgcn_sched_barrier(0);
  __builtin_amdgcn_s_barrier();

  for (int t = 0; t < 32; ++t) {
    const char* buf = smem + (t & 3)*32768;
    h16x8 af[8], bf[4];
    #pragma unroll
    for (int mf = 0; mf < 4; mf++) af[mf] = *(const h16x8*)(buf + abyte + mf*1024);
    #pragma unroll
    for (int nf = 0; nf < 4; nf++) bf[nf] = *(const h16x8*)(buf + bbyte + nf*1024);
    if (t < 30) stageA(t + 2);
    asm volatile("s_waitcnt lgkmcnt(0)" ::: "memory");
    __builtin_amdgcn_sched_barrier(0);
    __builtin_amdgcn_s_setprio(1);
    #pragma unroll
    for (int mf = 0; mf < 4; mf++)
      #pragma unroll
      for (int nf = 0; nf < 4; nf++)
        acc[mf][nf] = MFMA16(af[mf], bf[nf], acc[mf][nf]);
    __builtin_amdgcn_s_setprio(0);
    #pragma unroll
    for (int mf = 0; mf < 4; mf++) af[4+mf] = *(const h16x8*)(buf + abyte + 4096 + mf*1024);
    if (t < 30) stageB(t + 2);
    asm volatile("s_waitcnt lgkmcnt(0)" ::: "memory");
    __builtin_amdgcn_sched_barrier(0);
    __builtin_amdgcn_s_setprio(1);
    #pragma unroll
    for (int mf = 0; mf < 4; mf++)
      #pragma unroll
      for (int nf = 0; nf < 4; nf++)
        acc[4+mf][nf] = MFMA16(af[4+mf], bf[nf], acc[4+mf][nf]);
    __builtin_amdgcn_s_setprio(0);
    if (t < 30)       asm volatile("s_waitcnt vmcnt(4)" ::: "memory");
    else if (t == 30) asm volatile("s_waitcnt vmcnt(0)" ::: "memory");
    if (t < 31) {
      __builtin_amdgcn_sched_barrier(0);
      __builtin_amdgcn_s_barrier();
    }
  }
}

// ---------------- QKV GEMM (M=16384, N=3072, K=1024), natural-layout out ---
__global__ __launch_bounds__(512, 2) void k_qkv(
    const h16* __restrict__ xh, const h16* __restrict__ w3,
    h16* __restrict__ qn, h16* __restrict__ kn, h16* __restrict__ vn)
{
  extern __shared__ __align__(16) char smem[];   // 128 KiB
  const int tid = threadIdx.x;
  const int w = tid >> 6, l = tid & 63;
  const int m0 = blockIdx.x * 256;
  const int nt = blockIdx.y;                     // 0..11
  const int wr = w >> 2, wc = w & 3;

  f32x4 acc[8][4] = {};
  gemm256_loop(xh + (size_t)m0*1024, w3 + (size_t)(nt*256)*1024, smem, w, l, acc);

  const int proj = nt >> 2;   // 0=q 1=k 2=v (uniform per block)
  h16* dst = proj == 0 ? qn : (proj == 1 ? kn : vn);
  const int cb = (nt & 3)*256 + wc*64;
  #pragma unroll
  for (int mf = 0; mf < 8; mf++)
    #pragma unroll
    for (int nf = 0; nf < 4; nf++)
      #pragma unroll
      for (int r = 0; r < 4; r++) {
        int row = wr*128 + mf*16 + ((l >> 4) << 2) + r;
        int col = cb + nf*16 + (l & 15);
        dst[(size_t)(m0 + row)*1024 + col] = (h16)acc[mf][nf][r];
      }
}

// ------- final GEMM with fused RMSNorm: out = rmsnorm(O) @ (wo.rw)^T -------
__global__ __launch_bounds__(512, 2) void k_out(
    const h16* __restrict__ oh, const h16* __restrict__ woh,
    float* __restrict__ out)
{
  extern __shared__ __align__(16) char smem[];
  __shared__ float pp[512];
  __shared__ float rs[256];
  const int tid = threadIdx.x;
  const int w = tid >> 6, l = tid & 63;
  const int m0 = blockIdx.x * 256;
  const int n0 = blockIdx.y * 256;
  const int wr = w >> 2, wc = w & 3;

  // pre-pass: per-token inverse RMS for rows m0..m0+255
  {
    const int row = tid >> 1, half = tid & 1;
    const h16* rp = oh + (size_t)(m0 + row)*1024 + half*512;
    float ss = 0.f;
    for (int i = 0; i < 64; i++) {
      h16x8 v = *(const h16x8*)(rp + i*8);
      #pragma unroll
      for (int j = 0; j < 8; j++) { float f = (float)v[j]; ss += f*f; }
    }
    pp[tid] = ss;
  }
  __syncthreads();
  if (tid < 256) rs[tid] = rsqrtf((pp[2*tid] + pp[2*tid+1])*(1.0f/1024.0f) + 1e-5f);
  // (rs visible to all by the mainloop's barriers)

  f32x4 acc[8][4] = {};
  gemm256_loop(oh + (size_t)m0*1024, woh + (size_t)n0*1024, smem, w, l, acc);

  #pragma unroll
  for (int mf = 0; mf < 8; mf++)
    #pragma unroll
    for (int nf = 0; nf < 4; nf++)
      #pragma unroll
      for (int r = 0; r < 4; r++) {
        int row = wr*128 + mf*16 + ((l >> 4) << 2) + r;
        int col = n0 + wc*64 + nf*16 + (l & 15);
        out[(size_t)(m0 + row)*1024 + col] = rs[row] * acc[mf][nf][r];
      }
}

// ===== fused transpose + per-chunk KV state + roped-K writeout ============
__global__ __launch_bounds__(256) void k_trkv(
    const h16* __restrict__ kn, const h16* __restrict__ vn,
    const float* __restrict__ fc,
    h16* __restrict__ vt, h16* __restrict__ Th, h16* __restrict__ kr)
{
  __shared__ __align__(16) h16 tl[128*64];     // row-major staging
  __shared__ __align__(16) h16 kT2[64*136];    // Ks^T (d, c) padded
  __shared__ __align__(16) h16 vT2[64*136];    // V^T  (e, c) padded
  __shared__ float dt[128];
  const int tid = threadIdx.x;
  const int st = blockIdx.x;   // chunk 0..63
  const int bh = blockIdx.y;   // 0..31
  const int b = bh >> 4, h = bh & 15;
  if (tid < 128) {
    float slope = exp2f(-0.5f * (float)(h + 1));
    dt[tid] = expf(-slope * (float)(127 - tid));
  }
  const size_t ibase = ((size_t)(b*8192 + st*128))*1024 + h*64;
  const size_t obase = (size_t)bh*64*8192 + st*128;
  const size_t krbase = ((size_t)bh*8192 + st*128)*64;
  const int cr = tid >> 3, c8 = tid & 7;

  for (int which = 0; which < 2; ++which) {
    const h16* src = which ? vn : kn;
    h16* dT2 = which ? vT2 : kT2;
    __syncthreads();
    #pragma unroll
    for (int i = 0; i < 4; i++) {
      int r = i*32 + cr;
      h16x8 v = *(const h16x8*)(src + ibase + (size_t)r*1024 + c8*8);
      if (!which) {
        v = rope8(v, fc + (size_t)(st*128 + r)*64 + c8*8);
        *(h16x8*)(kr + krbase + (size_t)r*64 + c8*8) = v;   // roped K out
      }
      int slot = (c8 + ((r >> 3) & 7)) & 7;
      *(h16x8*)(tl + r*64 + slot*8) = v;
    }
    __syncthreads();
    #pragma unroll
    for (int i = 0; i < 4; i++) {
      int chunk = i*256 + tid;
      int d = chunk >> 4;
      int j8 = chunk & 15;
      h16x8 o;
      #pragma unroll
      for (int jj = 0; jj < 8; jj++) {
        int c = j8*8 + jj;
        int pos = (d + ((c >> 3) & 7)*8) & 63;
        float fv = (float)tl[c*64 + pos];
        if (!which) fv *= dt[c];
        o[jj] = (h16)fv;
      }
      *(h16x8*)(dT2 + d*136 + j8*8) = o;
      if (which) *(h16x8*)(vt + obase + (size_t)d*8192 + j8*8) = o;
    }
  }
  __syncthreads();

  const int w = tid >> 6, l = tid & 63;
  f32x4 acc[4] = {};
  h16x8 a[4];
  #pragma unroll
  for (int ks = 0; ks < 4; ks++)
    a[ks] = *(const h16x8*)(vT2 + (w*16 + (l & 15))*136 + ks*32 + (l >> 4)*8);
  #pragma unroll
  for (int nf = 0; nf < 4; nf++) {
    #pragma unroll
    for (int ks = 0; ks < 4; ks++) {
      h16x8 bfr = *(const h16x8*)(kT2 + (nf*16 + (l & 15))*136 + ks*32 + (l >> 4)*8);
      acc[nf] = MFMA16(a[ks], bfr, acc[nf]);
    }
  }
  h16* Tb = Th + ((size_t)bh*64 + st)*4096;
  #pragma unroll
  for (int nf = 0; nf < 4; nf++)
    #pragma unroll
    for (int r = 0; r < 4; r++) {
      int e = w*16 + ((l >> 4) << 2) + r;
      int d = nf*16 + (l & 15);
      Tb[e*64 + d] = (h16)acc[nf][r];
    }
}

// ---------------- decay prefix scan over chunks (1 elem/thread, fp16 T) ---
__global__ __launch_bounds__(256) void k_scan(const h16* __restrict__ Th,
                                              h16* __restrict__ ph) {
  const int bh = blockIdx.x;
  const int j  = blockIdx.y * 256 + threadIdx.x;
  const int h = bh & 15;
  const float cdec = expf(-exp2f(-0.5f*(float)(h+1)) * 128.0f);
  const h16* Tb = Th + (size_t)bh*64*4096 + j;
  h16* pb = ph + (size_t)bh*64*4096 + j;
  float run = 0.f;
  for (int t = 0; t < 64; t++) {
    float kv = (float)Tb[(size_t)t*4096];
    pb[(size_t)t*4096] = (h16)run;
    run = cdec*run + kv;
  }
}

// ------- per-chunk attention (roped Q on the fly, pre-roped K; balanced) ---
__global__ __launch_bounds__(256) void k_att(
    const h16* __restrict__ qn, const h16* __restrict__ kr,
    const float* __restrict__ fc,
    const h16* __restrict__ vt, const h16* __restrict__ ph,
    h16* __restrict__ oh)
{
  __shared__ __align__(16) h16 P[128*144];
  __shared__ float dt[128], qd[128];
  const int tid = threadIdx.x;
  const int t = blockIdx.x;
  const int bh = blockIdx.y;
  const int b = bh >> 4, h = bh & 15;
  if (tid < 128) {
    float slope = exp2f(-0.5f*(float)(h+1));
    dt[tid] = expf(-slope*(float)tid);
    qd[tid] = expf(-slope*(float)(tid+1));
  }
  __syncthreads();
  const int w = tid >> 6, l = tid & 63;
  const int rb[2] = { w*16, (7 - w)*16 };   // balanced causal split: 9 nf each
  const h16* qb = qn + ((size_t)(b*8192 + t*128))*1024 + h*64;
  const h16* kb = kr + ((size_t)bh*8192 + t*128)*64;
  const h16* vb = vt + (size_t)bh*64*8192 + t*128;
  const h16* pb = ph + ((size_t)bh*64 + t)*4096;
  const float* fcb = fc + (size_t)(t*128)*64;

  h16x8 aq[2][2];
  #pragma unroll
  for (int g = 0; g < 2; g++)
    #pragma unroll
    for (int ks = 0; ks < 2; ks++) {
      int row = rb[g] + (l & 15);
      int d0 = ks*32 + (l >> 4)*8;
      aq[g][ks] = rope8(*(const h16x8*)(qb + (size_t)row*1024 + d0),
                        fcb + (size_t)row*64 + d0);
    }

  // QK^T — causal, balanced: group g needs nf*16 <= rb[g]
  f32x4 sc[2][8] = {};
  #pragma unroll
  for (int nf = 0; nf < 8; nf++) {
    const bool g0 = (nf <= w);
    const bool g1 = (nf <= 7 - w);
    if (g0 || g1) {
      #pragma unroll
      for (int ks = 0; ks < 2; ks++) {
        h16x8 bk = *(const h16x8*)(kb + (size_t)(nf*16 + (l & 15))*64 + ks*32 + (l >> 4)*8);
        if (g0) sc[0][nf] = MFMA16(aq[0][ks], bk, sc[0][nf]);
        if (g1) sc[1][nf] = MFMA16(aq[1][ks], bk, sc[1][nf]);
      }
    }
  }
  #pragma unroll
  for (int g = 0; g < 2; g++) {
    #pragma unroll
    for (int nf = 0; nf < 8; nf++) {
      #pragma unroll
      for (int r = 0; r < 4; r++) {
        int i = rb[g] + ((l >> 4) << 2) + r;
        int j = nf*16 + (l & 15);
        int diff = i - j;
        float v = diff >= 0 ? sc[g][nf][r]*dt[diff] : 0.f;
        P[i*144 + j] = (h16)v;
      }
    }
  }
  f32x4 ao[2][4] = {};
  #pragma unroll
  for (int kc = 0; kc < 4; kc++) {
    h16x8 ap0 = *(const h16x8*)(P + (size_t)(rb[0] + (l & 15))*144 + kc*32 + (l >> 4)*8);
    h16x8 ap1 = *(const h16x8*)(P + (size_t)(rb[1] + (l & 15))*144 + kc*32 + (l >> 4)*8);
    #pragma unroll
    for (int nf = 0; nf < 4; nf++) {
      h16x8 bv = *(const h16x8*)(vb + (size_t)(nf*16 + (l & 15))*8192 + kc*32 + (l >> 4)*8);
      ao[0][nf] = MFMA16(ap0, bv, ao[0][nf]);
      ao[1][nf] = MFMA16(ap1, bv, ao[1][nf]);
    }
  }
  f32x4 a2[2][4] = {};
  #pragma unroll
  for (int ks = 0; ks < 2; ks++) {
    #pragma unroll
    for (int nf = 0; nf < 4; nf++) {
      h16x8 bs = *(const h16x8*)(pb + (size_t)(nf*16 + (l & 15))*64 + ks*32 + (l >> 4)*8);
      a2[0][nf] = MFMA16(aq[0][ks], bs, a2[0][nf]);
      a2[1][nf] = MFMA16(aq[1][ks], bs, a2[1][nf]);
    }
  }
  #pragma unroll
  for (int g = 0; g < 2; g++) {
    #pragma unroll
    for (int nf = 0; nf < 4; nf++) {
      #pragma unroll
      for (int r = 0; r < 4; r++) {
        int i = rb[g] + ((l >> 4) << 2) + r;
        int e = nf*16 + (l & 15);
        float o = ao[g][nf][r] + qd[i]*a2[g][nf][r];
        int s = t*128 + i;
        oh[((size_t)(b*8192 + s))*1024 + h*64 + e] = (h16)o;
      }
    }
  }
}

// --------------------------------------------------------------------------
extern "C" void kernel_launch(void* const* d_in, const int* in_sizes, int n_in,
                              void* d_out, int out_size, void* d_ws, size_t ws_size,
                              hipStream_t stream) {
  const float* x  = (const float*)d_in[0];
  const float* fc = (const float*)d_in[1];
  const float* wq = (const float*)d_in[2];
  const float* wk = (const float*)d_in[3];
  const float* wv = (const float*)d_in[4];
  const float* wo = (const float*)d_in[5];
  const float* rw = (const float*)d_in[6];
  float* out = (float*)d_out;

  char* p = (char*)d_ws;
  const size_t SZ = 33554432;
  h16* xh  = (h16*)(p);                  // later reused for kr (roped K)
  h16* vn  = (h16*)(p + 3*SZ);           // V natural; later reused for Ph
  h16* Th  = (h16*)(p + 4*SZ);           // fp16 per-chunk KV states
  h16* vt  = (h16*)(p + 5*SZ);
  h16* oh  = (h16*)(p + 6*SZ);           // O fp16
  h16* w3  = (h16*)(p + 7*SZ);
  h16* woh = (h16*)(p + 7*SZ + 6291456);
  // Q/K natural layout live in d_out (free until k_out overwrites it)
  h16* qn = (h16*)out;
  h16* kn = (h16*)out + 16777216;

  (void)hipFuncSetAttribute((const void*)k_qkv, hipFuncAttributeMaxDynamicSharedMemorySize, 131072);
  (void)hipFuncSetAttribute((const void*)k_out, hipFuncAttributeMaxDynamicSharedMemorySize, 131072);

  hipLaunchKernelGGL(k_cvt, dim3(8192), dim3(256), 0, stream, x, xh, 16777216);
  hipLaunchKernelGGL(k_cvt4, dim3(512, 4), dim3(256), 0, stream,
                     wq, wk, wv, wo, rw, w3, w3 + 1048576, w3 + 2097152, woh);

  hipLaunchKernelGGL(k_qkv, dim3(64, 12), dim3(512), 131072, stream, xh, w3, qn, kn, vn);
  h16* kr = xh;  // xh dead after k_qkv
  hipLaunchKernelGGL(k_trkv, dim3(64, 32), dim3(256), 0, stream, kn, vn, fc, vt, Th, kr);
  h16* ph = vn;  // vn dead after k_trkv
  hipLaunchKernelGGL(k_scan, dim3(32, 16), dim3(256), 0, stream, Th, ph);
  hipLaunchKernelGGL(k_att, dim3(64, 32), dim3(256), 0, stream, qn, kr, fc, vt, ph, oh);
  hipLaunchKernelGGL(k_out, dim3(64, 4), dim3(512), 131072, stream, oh, woh, out);
}